// Round 1
// baseline (152.023 us; speedup 1.0000x reference)
//
#include <hip/hip_runtime.h>

// RelationGAT, algebraically collapsed:
//   A  = Wq^T @ Wk            (A[j][d]  = sum_o Wq[o][j]*Wk[o][d])
//   M  = Wv @ Wk,  MT = M^T   (MT[d][t] = sum_o Wv[t][o]*Wk[o][d])
//   P  = X @ A                                  [B,128]
//   scores[b,n] = P[b,:] . nbr[b,n,:];  attn = softmax_n
//   NBAR[b,:]   = sum_n attn[b,n]*nbr[b,n,:]
//   OUT = NBAR @ MT  (out[b,t] = sum_d NBAR[b,d]*MT[d][t])

#define NB 16384
#define NNBR 50
#define DIM 128

// ---------------- wave-wide allreduce (sum over 64 lanes, all lanes get it) --
template <int CTRL>
__device__ __forceinline__ float dpp_add(float x) {
  int v = __builtin_amdgcn_update_dpp(0, __builtin_bit_cast(int, x), CTRL,
                                      0xF, 0xF, true);
  return x + __builtin_bit_cast(float, v);
}

__device__ __forceinline__ float wave_sum(float x) {
  x = dpp_add<0xB1>(x);   // quad_perm {1,0,3,2}  : xor 1
  x = dpp_add<0x4E>(x);   // quad_perm {2,3,0,1}  : xor 2
  x = dpp_add<0x141>(x);  // row_half_mirror      : xor 4..7 within 8
  x = dpp_add<0x140>(x);  // row_mirror           : xor 8..15 within 16
  x += __shfl_xor(x, 16, 64);
  x += __shfl_xor(x, 32, 64);
  return x;
}

// ---------------- K1: A and MT from the three weight matrices ----------------
__global__ void precompute_weights(const float* __restrict__ Wq,
                                   const float* __restrict__ Wk,
                                   const float* __restrict__ Wv,
                                   float* __restrict__ A,
                                   float* __restrict__ MT) {
  int g = blockIdx.x;
  int d = threadIdx.x;  // 0..127
  if (g < 128) {
    int j = g;
    float acc = 0.f;
    for (int o = 0; o < 128; ++o)
      acc += Wq[o * 128 + j] * Wk[o * 128 + d];
    A[j * 128 + d] = acc;
  } else {
    int t = g - 128;
    float acc = 0.f;
    for (int o = 0; o < 128; ++o)
      acc += Wv[t * 128 + o] * Wk[o * 128 + d];
    MT[d * 128 + t] = acc;  // transposed store (tiny matrix, scatter is fine)
  }
}

// ---------------- K2/K4: C[b,c] = sum_j L[b,j] * R[j*128+c]  (M=16384,K=N=128)
__global__ __launch_bounds__(256) void gemm128(const float* __restrict__ L,
                                               const float* __restrict__ R,
                                               float* __restrict__ C) {
  int t = threadIdx.x;
  int cg = t & 31;        // column group -> 4 consecutive cols
  int s = t >> 5;         // 0..7 -> row subtile
  int c0 = cg * 4;
  int b0 = blockIdx.x * 32 + s * 4;  // 32 rows per block, 4 rows per thread

  float4 acc[4];
  #pragma unroll
  for (int i = 0; i < 4; ++i) acc[i] = make_float4(0.f, 0.f, 0.f, 0.f);

  for (int j = 0; j < 128; j += 4) {
    float4 r0 = *(const float4*)(R + (j + 0) * 128 + c0);
    float4 r1 = *(const float4*)(R + (j + 1) * 128 + c0);
    float4 r2 = *(const float4*)(R + (j + 2) * 128 + c0);
    float4 r3 = *(const float4*)(R + (j + 3) * 128 + c0);
    #pragma unroll
    for (int i = 0; i < 4; ++i) {
      float4 lv = *(const float4*)(L + (size_t)(b0 + i) * 128 + j);
      acc[i].x += lv.x * r0.x + lv.y * r1.x + lv.z * r2.x + lv.w * r3.x;
      acc[i].y += lv.x * r0.y + lv.y * r1.y + lv.z * r2.y + lv.w * r3.y;
      acc[i].z += lv.x * r0.z + lv.y * r1.z + lv.z * r2.z + lv.w * r3.z;
      acc[i].w += lv.x * r0.w + lv.y * r1.w + lv.z * r2.w + lv.w * r3.w;
    }
  }
  #pragma unroll
  for (int i = 0; i < 4; ++i)
    *(float4*)(C + (size_t)(b0 + i) * 128 + c0) = acc[i];
}

// ---------------- K3: stream neighbor once; online softmax + weighted sum ----
// One wave per batch row. Lane owns dims {2*lane, 2*lane+1}.
__global__ __launch_bounds__(256, 4) void attn_rows(const float* __restrict__ P,
                                                    const float* __restrict__ nbr,
                                                    float* __restrict__ NBAR) {
  int wave = threadIdx.x >> 6;
  int lane = threadIdx.x & 63;
  int b = blockIdx.x * 4 + wave;

  float2 p = ((const float2*)(P + (size_t)b * DIM))[lane];
  const float2* nrow = (const float2*)(nbr + (size_t)b * NNBR * DIM);

  float m = -INFINITY, l = 0.f;
  float acc0 = 0.f, acc1 = 0.f;

  #pragma unroll
  for (int n = 0; n < NNBR; ++n) {
    float2 v = nrow[n * (DIM / 2) + lane];          // coalesced 512B per wave
    float partial = p.x * v.x + p.y * v.y;
    float s = wave_sum(partial);                    // score, uniform on wave
    float mn = fmaxf(m, s);
    float scale = __expf(m - mn);                   // first iter: exp(-inf)=0
    float e = __expf(s - mn);
    l = l * scale + e;
    acc0 = acc0 * scale + e * v.x;
    acc1 = acc1 * scale + e * v.y;
    m = mn;
  }

  float inv = 1.f / l;
  float2 o = make_float2(acc0 * inv, acc1 * inv);
  ((float2*)(NBAR + (size_t)b * DIM))[lane] = o;
}

// ---------------- launcher ---------------------------------------------------
extern "C" void kernel_launch(void* const* d_in, const int* in_sizes, int n_in,
                              void* d_out, int out_size, void* d_ws,
                              size_t ws_size, hipStream_t stream) {
  const float* x   = (const float*)d_in[0];
  const float* nbr = (const float*)d_in[1];
  const float* Wq  = (const float*)d_in[2];
  const float* Wk  = (const float*)d_in[3];
  const float* Wv  = (const float*)d_in[4];
  float* out = (float*)d_out;

  char* ws = (char*)d_ws;
  float* A    = (float*)(ws);                          // 64 KB
  float* MT   = (float*)(ws + 65536);                  // 64 KB
  float* P    = (float*)(ws + 131072);                 // 8 MB
  float* NBAR = (float*)(ws + 131072 + 8388608);       // 8 MB  (total ~16.1 MB)

  precompute_weights<<<256, 128, 0, stream>>>(Wq, Wk, Wv, A, MT);
  gemm128<<<NB / 32, 256, 0, stream>>>(x, A, P);       // P = X @ A
  attn_rows<<<NB / 4, 256, 0, stream>>>(P, nbr, NBAR); // softmax-weighted sum
  gemm128<<<NB / 32, 256, 0, stream>>>(NBAR, MT, out); // OUT = NBAR @ MT
}

// Round 2
// 151.395 us; speedup vs baseline: 1.0041x; 1.0041x over previous
//
#include <hip/hip_runtime.h>

// RelationGAT, algebraically collapsed:
//   A  = Wq^T @ Wk            (A[j][d]  = sum_o Wq[o][j]*Wk[o][d])
//   M  = Wv @ Wk,  MT = M^T   (MT[d][t] = sum_o Wv[t][o]*Wk[o][d])
//   P  = X @ A                                  [B,128]
//   scores[b,n] = P[b,:] . nbr[b,n,:];  attn = softmax_n
//   NBAR[b,:]   = sum_n attn[b,n]*nbr[b,n,:]
//   OUT = NBAR @ MT  (out[b,t] = sum_d NBAR[b,d]*MT[d][t])

#define NB 16384
#define NNBR 50
#define DIM 128

// ---------------- cross-lane add helpers -------------------------------------
template <int CTRL>
__device__ __forceinline__ float dpp_add(float x) {
  int v = __builtin_amdgcn_update_dpp(0, __builtin_bit_cast(int, x), CTRL,
                                      0xF, 0xF, true);
  return x + __builtin_bit_cast(float, v);
}

// sum over each 32-lane half (all lanes of the half get the result)
__device__ __forceinline__ float half_sum(float x) {
  x = dpp_add<0xB1>(x);   // quad_perm {1,0,3,2}  : xor 1
  x = dpp_add<0x4E>(x);   // quad_perm {2,3,0,1}  : xor 2
  x = dpp_add<0x141>(x);  // row_half_mirror      : folds 4-groups within 8
  x = dpp_add<0x140>(x);  // row_mirror           : folds 8-groups within 16
  x += __shfl_xor(x, 16, 64);                    // folds 16-groups within 32
  return x;
}

// ---------------- K1: A and MT from the three weight matrices ----------------
__global__ void precompute_weights(const float* __restrict__ Wq,
                                   const float* __restrict__ Wk,
                                   const float* __restrict__ Wv,
                                   float* __restrict__ A,
                                   float* __restrict__ MT) {
  int g = blockIdx.x;
  int d = threadIdx.x;  // 0..127
  if (g < 128) {
    int j = g;
    float acc = 0.f;
    for (int o = 0; o < 128; ++o)
      acc += Wq[o * 128 + j] * Wk[o * 128 + d];
    A[j * 128 + d] = acc;
  } else {
    int t = g - 128;
    float acc = 0.f;
    for (int o = 0; o < 128; ++o)
      acc += Wv[t * 128 + o] * Wk[o * 128 + d];
    MT[d * 128 + t] = acc;  // transposed store (tiny matrix, scatter is fine)
  }
}

// ---------------- K2/K4: C[b,c] = sum_j L[b,j] * R[j*128+c]  (M=16384,K=N=128)
__global__ __launch_bounds__(256) void gemm128(const float* __restrict__ L,
                                               const float* __restrict__ R,
                                               float* __restrict__ C) {
  int t = threadIdx.x;
  int cg = t & 31;        // column group -> 4 consecutive cols
  int s = t >> 5;         // 0..7 -> row subtile
  int c0 = cg * 4;
  int b0 = blockIdx.x * 32 + s * 4;  // 32 rows per block, 4 rows per thread

  float4 acc[4];
  #pragma unroll
  for (int i = 0; i < 4; ++i) acc[i] = make_float4(0.f, 0.f, 0.f, 0.f);

  for (int j = 0; j < 128; j += 4) {
    float4 r0 = *(const float4*)(R + (j + 0) * 128 + c0);
    float4 r1 = *(const float4*)(R + (j + 1) * 128 + c0);
    float4 r2 = *(const float4*)(R + (j + 2) * 128 + c0);
    float4 r3 = *(const float4*)(R + (j + 3) * 128 + c0);
    #pragma unroll
    for (int i = 0; i < 4; ++i) {
      float4 lv = *(const float4*)(L + (size_t)(b0 + i) * 128 + j);
      acc[i].x += lv.x * r0.x + lv.y * r1.x + lv.z * r2.x + lv.w * r3.x;
      acc[i].y += lv.x * r0.y + lv.y * r1.y + lv.z * r2.y + lv.w * r3.y;
      acc[i].z += lv.x * r0.z + lv.y * r1.z + lv.z * r2.z + lv.w * r3.z;
      acc[i].w += lv.x * r0.w + lv.y * r1.w + lv.z * r2.w + lv.w * r3.w;
    }
  }
  #pragma unroll
  for (int i = 0; i < 4; ++i)
    *(float4*)(C + (size_t)(b0 + i) * 128 + c0) = acc[i];
}

// ---------------- K3: stream neighbor once; online softmax + weighted sum ----
// One wave per batch row. Lane owns 4 dims (float4, 16B/lane): one wave-load
// covers 256 floats = TWO neighbor rows. Lanes 0-31 process even neighbors,
// lanes 32-63 odd neighbors; the online-softmax max is shared wave-wide so
// both half-accumulators stay consistently scaled; halves merge at the end.
__global__ __launch_bounds__(256, 4) void attn_rows(const float* __restrict__ P,
                                                    const float* __restrict__ nbr,
                                                    float* __restrict__ NBAR) {
  int wave = threadIdx.x >> 6;
  int lane = threadIdx.x & 63;
  int b = blockIdx.x * 4 + wave;

  float4 p = ((const float4*)(P + (size_t)b * DIM))[lane & 31];
  const float4* nrow = (const float4*)(nbr + (size_t)b * NNBR * DIM);

  float m = -INFINITY, l = 0.f;
  float4 acc = make_float4(0.f, 0.f, 0.f, 0.f);

  float4 v = nrow[lane];  // pair 0 (neighbors 0,1)
  #pragma unroll 5
  for (int np = 0; np < 25; ++np) {
    int nxt = (np + 1 < 25) ? (np + 1) : np;     // clamp: last prefetch re-reads
    float4 vn = nrow[nxt * 64 + lane];           // prefetch next pair (1KB/wave)

    float partial = p.x * v.x + p.y * v.y + p.z * v.z + p.w * v.w;
    float s = half_sum(partial);                 // per-half score
    float so = __shfl_xor(s, 32, 64);            // other half's score
    float mn = fmaxf(m, fmaxf(s, so));           // wave-uniform running max
    float scale = __expf(m - mn);                // first iter: exp(-inf)=0
    float e = __expf(s - mn);                    // this half's weight
    l = l * scale + e;
    acc.x = acc.x * scale + e * v.x;
    acc.y = acc.y * scale + e * v.y;
    acc.z = acc.z * scale + e * v.z;
    acc.w = acc.w * scale + e * v.w;
    m = mn;
    v = vn;
  }

  // merge the two half-wave accumulators (lane d <- lane d + lane d^32)
  l += __shfl_xor(l, 32, 64);
  acc.x += __shfl_xor(acc.x, 32, 64);
  acc.y += __shfl_xor(acc.y, 32, 64);
  acc.z += __shfl_xor(acc.z, 32, 64);
  acc.w += __shfl_xor(acc.w, 32, 64);

  if (lane < 32) {
    float inv = 1.f / l;
    float4 o = make_float4(acc.x * inv, acc.y * inv, acc.z * inv, acc.w * inv);
    ((float4*)(NBAR + (size_t)b * DIM))[lane] = o;  // 512B coalesced per row
  }
}

// ---------------- launcher ---------------------------------------------------
extern "C" void kernel_launch(void* const* d_in, const int* in_sizes, int n_in,
                              void* d_out, int out_size, void* d_ws,
                              size_t ws_size, hipStream_t stream) {
  const float* x   = (const float*)d_in[0];
  const float* nbr = (const float*)d_in[1];
  const float* Wq  = (const float*)d_in[2];
  const float* Wk  = (const float*)d_in[3];
  const float* Wv  = (const float*)d_in[4];
  float* out = (float*)d_out;

  char* ws = (char*)d_ws;
  float* A    = (float*)(ws);                          // 64 KB
  float* MT   = (float*)(ws + 65536);                  // 64 KB
  float* P    = (float*)(ws + 131072);                 // 8 MB
  float* NBAR = (float*)(ws + 131072 + 8388608);       // 8 MB  (total ~16.1 MB)

  precompute_weights<<<256, 128, 0, stream>>>(Wq, Wk, Wv, A, MT);
  gemm128<<<NB / 32, 256, 0, stream>>>(x, A, P);       // P = X @ A
  attn_rows<<<NB / 4, 256, 0, stream>>>(P, nbr, NBAR); // softmax-weighted sum
  gemm128<<<NB / 32, 256, 0, stream>>>(NBAR, MT, out); // OUT = NBAR @ MT
}

// Round 3
// 148.166 us; speedup vs baseline: 1.0260x; 1.0218x over previous
//
#include <hip/hip_runtime.h>

// RelationGAT, algebraically collapsed:
//   A  = Wq^T @ Wk            (A[j][d]  = sum_o Wq[o][j]*Wk[o][d])
//   M  = Wv @ Wk,  MT = M^T   (MT[d][t] = sum_o Wv[t][o]*Wk[o][d])
//   P  = X @ A                                  [B,128]
//   scores[b,n] = P[b,:] . nbr[b,n,:];  attn = softmax_n
//   NBAR[b,:]   = sum_n attn[b,n]*nbr[b,n,:]
//   OUT = NBAR @ MT  (out[b,t] = sum_d NBAR[b,d]*MT[d][t])

#define NB 16384
#define NNBR 50
#define DIM 128

// ---------------- cross-lane add helpers -------------------------------------
template <int CTRL>
__device__ __forceinline__ float dpp_add(float x) {
  int v = __builtin_amdgcn_update_dpp(0, __builtin_bit_cast(int, x), CTRL,
                                      0xF, 0xF, true);
  return x + __builtin_bit_cast(float, v);
}

// sum over each 32-lane half (all lanes of the half get the result)
__device__ __forceinline__ float half_sum(float x) {
  x = dpp_add<0xB1>(x);   // quad_perm {1,0,3,2}  : xor 1
  x = dpp_add<0x4E>(x);   // quad_perm {2,3,0,1}  : xor 2
  x = dpp_add<0x141>(x);  // row_half_mirror      : folds 4-groups within 8
  x = dpp_add<0x140>(x);  // row_mirror           : folds 8-groups within 16
  x += __shfl_xor(x, 16, 64);                    // folds 16-groups within 32
  return x;
}

// ---------------- K1: A and MT, LDS-staged (latency-tolerant) ----------------
// 32 blocks x 256 threads (8 waves). Blocks 0-15 -> 8 rows of A each;
// blocks 16-31 -> 8 "t" rows of M (stored transposed into MT).
// Each block stages the full Wk (64 KB) in LDS via deep float4 pipelining,
// plus 8 rows of Wq^T (resp. Wv) into a 4 KB LDS strip.
__global__ __launch_bounds__(256) void precompute_weights(
    const float* __restrict__ Wq, const float* __restrict__ Wk,
    const float* __restrict__ Wv, float* __restrict__ A,
    float* __restrict__ MT) {
  __shared__ float wk[128 * 128];   // 64 KB
  __shared__ float wrow[8 * 128];   // 4 KB
  int t = threadIdx.x;
  int g = blockIdx.x;
  bool isA = g < 16;
  int r0 = (g & 15) * 8;

  // stage Wk: 16384 floats = 256 threads x 16 float4, all loads issued early
  const float4* wk4 = (const float4*)Wk;
  float4* wkl4 = (float4*)wk;
  #pragma unroll
  for (int i = 0; i < 16; ++i) wkl4[t + i * 256] = wk4[t + i * 256];

  // stage the 8 left-operand rows
  if (isA) {
    #pragma unroll
    for (int i = 0; i < 4; ++i) {            // wrow[q][o] = Wq[o][r0+q]
      int idx = t + i * 256;                 // 0..1023
      int q = idx >> 7, o = idx & 127;
      wrow[q * 128 + o] = Wq[o * 128 + r0 + q];
    }
  } else {
    const float4* wv4 = (const float4*)(Wv + r0 * 128);
    float4* wr4 = (float4*)wrow;             // wrow[q][o] = Wv[r0+q][o]
    if (t < 256) wr4[t] = wv4[t];
  }
  __syncthreads();

  // compute 4 outputs per thread: d = t&127, rows r0+h..r0+h+3 (h per half)
  int d = t & 127;
  int h = (t >> 7) * 4;
  float acc[4] = {0.f, 0.f, 0.f, 0.f};
  #pragma unroll 8
  for (int o = 0; o < 128; ++o) {
    float b = wk[o * 128 + d];               // stride-1 across lanes: no conflict
    #pragma unroll
    for (int qq = 0; qq < 4; ++qq)
      acc[qq] += wrow[(h + qq) * 128 + o] * b;  // wave-uniform: broadcast
  }
  if (isA) {
    #pragma unroll
    for (int qq = 0; qq < 4; ++qq) A[(r0 + h + qq) * 128 + d] = acc[qq];
  } else {
    #pragma unroll
    for (int qq = 0; qq < 4; ++qq) MT[d * 128 + r0 + h + qq] = acc[qq];
  }
}

// ---------------- K2/K4: C[b,c] = sum_j L[b,j] * R[j*128+c]  (M=16384,K=N=128)
__global__ __launch_bounds__(256) void gemm128(const float* __restrict__ L,
                                               const float* __restrict__ R,
                                               float* __restrict__ C) {
  int t = threadIdx.x;
  int cg = t & 31;        // column group -> 4 consecutive cols
  int s = t >> 5;         // 0..7 -> row subtile
  int c0 = cg * 4;
  int b0 = blockIdx.x * 32 + s * 4;  // 32 rows per block, 4 rows per thread

  float4 acc[4];
  #pragma unroll
  for (int i = 0; i < 4; ++i) acc[i] = make_float4(0.f, 0.f, 0.f, 0.f);

  for (int j = 0; j < 128; j += 4) {
    float4 r0 = *(const float4*)(R + (j + 0) * 128 + c0);
    float4 r1 = *(const float4*)(R + (j + 1) * 128 + c0);
    float4 r2 = *(const float4*)(R + (j + 2) * 128 + c0);
    float4 r3 = *(const float4*)(R + (j + 3) * 128 + c0);
    #pragma unroll
    for (int i = 0; i < 4; ++i) {
      float4 lv = *(const float4*)(L + (size_t)(b0 + i) * 128 + j);
      acc[i].x += lv.x * r0.x + lv.y * r1.x + lv.z * r2.x + lv.w * r3.x;
      acc[i].y += lv.x * r0.y + lv.y * r1.y + lv.z * r2.y + lv.w * r3.y;
      acc[i].z += lv.x * r0.z + lv.y * r1.z + lv.z * r2.z + lv.w * r3.z;
      acc[i].w += lv.x * r0.w + lv.y * r1.w + lv.z * r2.w + lv.w * r3.w;
    }
  }
  #pragma unroll
  for (int i = 0; i < 4; ++i)
    *(float4*)(C + (size_t)(b0 + i) * 128 + c0) = acc[i];
}

// ---------------- K3: stream neighbor once; online softmax + weighted sum ----
// One wave per batch row. Lane owns 4 dims (float4, 16B/lane): one wave-load
// covers 256 floats = TWO neighbor rows. Lanes 0-31 process even neighbors,
// lanes 32-63 odd neighbors; the online-softmax max is shared wave-wide so
// both half-accumulators stay consistently scaled; halves merge at the end.
__global__ __launch_bounds__(256) void attn_rows(const float* __restrict__ P,
                                                 const float* __restrict__ nbr,
                                                 float* __restrict__ NBAR) {
  int wave = threadIdx.x >> 6;
  int lane = threadIdx.x & 63;
  int b = blockIdx.x * 4 + wave;

  float4 p = ((const float4*)(P + (size_t)b * DIM))[lane & 31];
  const float4* nrow = (const float4*)(nbr + (size_t)b * NNBR * DIM);

  float m = -INFINITY, l = 0.f;
  float4 acc = make_float4(0.f, 0.f, 0.f, 0.f);

  float4 v = nrow[lane];  // pair 0 (neighbors 0,1)
  #pragma unroll 5
  for (int np = 0; np < 25; ++np) {
    int nxt = (np + 1 < 25) ? (np + 1) : np;     // clamp: last prefetch re-reads
    float4 vn = nrow[nxt * 64 + lane];           // prefetch next pair (1KB/wave)

    float partial = p.x * v.x + p.y * v.y + p.z * v.z + p.w * v.w;
    float s = half_sum(partial);                 // per-half score
    float so = __shfl_xor(s, 32, 64);            // other half's score
    float mn = fmaxf(m, fmaxf(s, so));           // wave-uniform running max
    float scale = __expf(m - mn);                // first iter: exp(-inf)=0
    float e = __expf(s - mn);                    // this half's weight
    l = l * scale + e;
    acc.x = acc.x * scale + e * v.x;
    acc.y = acc.y * scale + e * v.y;
    acc.z = acc.z * scale + e * v.z;
    acc.w = acc.w * scale + e * v.w;
    m = mn;
    v = vn;
  }

  // merge the two half-wave accumulators (lane d <- lane d + lane d^32)
  l += __shfl_xor(l, 32, 64);
  acc.x += __shfl_xor(acc.x, 32, 64);
  acc.y += __shfl_xor(acc.y, 32, 64);
  acc.z += __shfl_xor(acc.z, 32, 64);
  acc.w += __shfl_xor(acc.w, 32, 64);

  if (lane < 32) {
    float inv = 1.f / l;
    float4 o = make_float4(acc.x * inv, acc.y * inv, acc.z * inv, acc.w * inv);
    ((float4*)(NBAR + (size_t)b * DIM))[lane] = o;  // 512B coalesced per row
  }
}

// ---------------- launcher ---------------------------------------------------
extern "C" void kernel_launch(void* const* d_in, const int* in_sizes, int n_in,
                              void* d_out, int out_size, void* d_ws,
                              size_t ws_size, hipStream_t stream) {
  const float* x   = (const float*)d_in[0];
  const float* nbr = (const float*)d_in[1];
  const float* Wq  = (const float*)d_in[2];
  const float* Wk  = (const float*)d_in[3];
  const float* Wv  = (const float*)d_in[4];
  float* out = (float*)d_out;

  char* ws = (char*)d_ws;
  float* A    = (float*)(ws);                          // 64 KB
  float* MT   = (float*)(ws + 65536);                  // 64 KB
  float* P    = (float*)(ws + 131072);                 // 8 MB
  float* NBAR = (float*)(ws + 131072 + 8388608);       // 8 MB  (total ~16.1 MB)

  precompute_weights<<<32, 256, 0, stream>>>(Wq, Wk, Wv, A, MT);
  gemm128<<<NB / 32, 256, 0, stream>>>(x, A, P);       // P = X @ A
  attn_rows<<<NB / 4, 256, 0, stream>>>(P, nbr, NBAR); // softmax-weighted sum
  gemm128<<<NB / 32, 256, 0, stream>>>(NBAR, MT, out); // OUT = NBAR @ MT
}